// Round 11
// baseline (558.575 us; speedup 1.0000x reference)
//
#include <hip/hip_runtime.h>
#include <hip/hip_bf16.h>
#include <math.h>

#define DCH 256
#define HWD 128

typedef __attribute__((ext_vector_type(4))) float f32x4;
typedef __attribute__((ext_vector_type(4))) short s16x4;
typedef long long i64f;   // 8 packed fp8 (2 VGPR) MFMA operand

__device__ __forceinline__ float b2f(unsigned short u) {
    union { float f; unsigned int i; } c; c.i = ((unsigned int)u) << 16; return c.f;
}
__device__ __forceinline__ unsigned short f2b(float f) {
    union { __hip_bfloat16 h; unsigned short u; } c; c.h = __float2bfloat16(f); return c.u;
}
__device__ __forceinline__ unsigned int f2b2(float lo, float hi) {
    return (unsigned int)f2b(lo) | ((unsigned int)f2b(hi) << 16);
}
// fp8 e4m3 (OCP on gfx950) conversions
__device__ __forceinline__ unsigned char f2e4(float f) {
    return (unsigned char)(__builtin_amdgcn_cvt_pk_fp8_f32(f, 0.f, 0, false) & 0xFF);
}
__device__ __forceinline__ unsigned int f2e4x4(float a, float b, float c, float d) {
    unsigned int lo = (unsigned int)__builtin_amdgcn_cvt_pk_fp8_f32(a, b, 0, false);
    return (unsigned int)__builtin_amdgcn_cvt_pk_fp8_f32(c, d, (int)lo, true);
}
__device__ __forceinline__ float e42f(unsigned char u) {
    return __builtin_amdgcn_cvt_f32_fp8((int)u, 0);
}
// tanh-form gelu via native v_exp_f32 (R8-proven numerics)
__device__ __forceinline__ float gelu_f(float z) {
    float y = z * (1.0f + 0.044715f * z * z);
    float p = exp2f(-2.3022108f * y);
    return z / (1.0f + p);
}

// ---- weight prep: fp32 -> scaled fp8 (W1,W2 x16; Ws x256), W1/W2 transposed ----
__global__ void prep_weights(const float* __restrict__ W1, const float* __restrict__ W2,
                             const float* __restrict__ Wsf, const float* __restrict__ Wsh,
                             const float* __restrict__ Wsq,
                             unsigned char* __restrict__ w1t, unsigned char* __restrict__ w2t,
                             unsigned char* __restrict__ wsf, unsigned char* __restrict__ wsh,
                             unsigned char* __restrict__ wsq)
{
    int idx = blockIdx.x * 256 + threadIdx.x;
    if (idx < 3 * 512 * 256) {               // w1t[g][n][k] = 16*W1[g][k][n]
        int g = idx / (512 * 256); int r = idx % (512 * 256);
        int n = r / 256, k = r % 256;
        w1t[idx] = f2e4(16.0f * W1[((size_t)g * 256 + k) * 512 + n]);
    }
    if (idx < 3 * 256 * 256) {               // w2t[g][n][k] = 16*W2[g][k][n]
        int g = idx / (256 * 256); int r = idx % (256 * 256);
        int n = r / 256, k = r % 256;
        w2t[idx] = f2e4(16.0f * W2[((size_t)g * 256 + k) * 256 + n]);
    }
    if (idx < 64 * 64) wsf[idx] = f2e4(256.0f * Wsf[idx]);
    if (idx < 32 * 32) wsh[idx] = f2e4(256.0f * Wsh[idx]);
    if (idx < 16 * 16) wsq[idx] = f2e4(256.0f * Wsq[idx]);
}

// ---------------- fused per-segment gMLP body: 1024 threads (16 waves), fp8 LDS ----------------
// R8 structure at 2x threads: each wave owns 16 output columns per GEMM pass (was 32).
// LDS: X_t bf16 [256][LSEG+4] ; Y fp8 [LSEG][264] -> P(fp8) ; Vt fp8 [256][LSEG+8]
//   part1 over Vt (ph1-2), part4 over Y (ph4) [LSEG=16: both in tail], O_t bf16 over Y+Vt.
template<int LSEG, int GROUP, int PC>
__device__ __forceinline__
void gmlp_body(int b, int hr0, int wr0,
               const float* __restrict__ x,
               const float* __restrict__ ln1_g, const float* __restrict__ ln1_b,
               const float* __restrict__ b1,
               const float* __restrict__ sgu_g, const float* __restrict__ sgu_b,
               const float* __restrict__ bs, const float* __restrict__ b2,
               const unsigned char* __restrict__ w1t,
               const unsigned char* __restrict__ w2t,
               const unsigned char* __restrict__ wsp,
               float* __restrict__ out,
               unsigned char* smem)
{
    constexpr int NT  = 1024;
    constexpr int TPT = NT / LSEG;            // threads per token
    constexpr int CPT = DCH / TPT;            // channels per thread
    constexpr int YP  = 264;                  // Y fp8 row stride (bytes)
    constexpr int M16 = LSEG / 16;
    constexpr int XTP = LSEG + 4;             // X_t / O_t row stride (u16 elements)
    constexpr int VTP = LSEG + 8;             // Vt row stride (bytes)
    constexpr int SZXT = 256 * XTP * 2;
    constexpr int SZY  = LSEG * YP;
    constexpr int SZVT = 256 * VTP;
    constexpr int SZSTAT = 2 * NT * 4;        // 8 KB
    static_assert(SZXT + SZY + SZVT + (LSEG == 16 ? SZSTAT : 0) <= 70144, "LDS budget");
    static_assert(SZY + SZVT >= 256 * XTP * 2, "O_t must fit over Y+Vt");
    static_assert(LSEG == 16 || (SZVT >= SZSTAT && SZY >= SZSTAT), "stats fit");

    unsigned short* xt16 = (unsigned short*)smem;      // X_t (bf16, channel-major)
    unsigned char*  sm_y8 = smem + SZXT;               // Y (fp8), later P (fp8)
    unsigned char*  vt8   = smem + SZXT + SZY;         // Vt (fp8)
    unsigned short* ot16 = (unsigned short*)(smem + SZXT); // O_t bf16 (after barrier)
    float* part1; float* part4;
    if constexpr (LSEG == 16) {
        part1 = (float*)(smem + SZXT + SZY + SZVT);    // dedicated tail
        part4 = part1;
    } else {
        part1 = (float*)(smem + SZXT + SZY);           // over Vt (dead ph1-2)
        part4 = (float*)(smem + SZXT);                 // over Y (dead ph4)
    }

    const int tid  = threadIdx.x;
    const int lane = tid & 63;
    const int wv   = tid >> 6;                // 0..15
    const int l16  = lane & 15;
    const int l4   = lane >> 4;
    const int t    = tid & (LSEG - 1);
    const int dq   = tid / LSEG;
    const int d0   = dq * CPT;

    const int pr = t / PC, pc = t % PC;
    const int hq = (hr0 + pr + 4) & (HWD - 1);
    const int wq = (wr0 + pc + 4) & (HWD - 1);
    const size_t plane = (size_t)HWD * HWD;
    const float* xp = x + (size_t)b * DCH * plane + (size_t)hq * HWD + wq;

    // ---- Phase 1: gather x + per-token partial stats; residual regs + X_t ----
    unsigned int xres[CPT / 2];
    {
        float s1 = 0.f, s2 = 0.f;
        #pragma unroll
        for (int i = 0; i < CPT; i += 2) {
            float v0 = xp[(size_t)(d0 + i) * plane];
            float v1 = xp[(size_t)(d0 + i + 1) * plane];
            s1 += v0 + v1; s2 += v0 * v0 + v1 * v1;
            unsigned int pk = f2b2(v0, v1);
            xres[i / 2] = pk;
            xt16[(d0 + i) * XTP + t]     = (unsigned short)(pk & 0xFFFF);
            xt16[(d0 + i + 1) * XTP + t] = (unsigned short)(pk >> 16);
        }
        part1[(0 * TPT + dq) * LSEG + t] = s1;
        part1[(1 * TPT + dq) * LSEG + t] = s2;
    }
    __syncthreads();

    // ---- Phase 2: LN1 -> Y (fp8) ----
    {
        float mu = 0.f, sq = 0.f;
        #pragma unroll
        for (int q = 0; q < TPT; ++q) {
            mu += part1[(0 * TPT + q) * LSEG + t];
            sq += part1[(1 * TPT + q) * LSEG + t];
        }
        mu *= (1.0f / DCH);
        float var = sq * (1.0f / DCH) - mu * mu;
        float rs = rsqrtf(var + 1e-5f);
        #pragma unroll
        for (int i = 0; i < CPT; i += 4) {
            f32x4 g  = *(const f32x4*)&ln1_g[GROUP * DCH + d0 + i];
            f32x4 bv = *(const f32x4*)&ln1_b[GROUP * DCH + d0 + i];
            float z[4];
            #pragma unroll
            for (int j = 0; j < 4; ++j) {
                unsigned int pk = xres[(i + j) / 2];
                float v = b2f((unsigned short)((j & 1) ? (pk >> 16) : (pk & 0xFFFF)));
                z[j] = (v - mu) * rs * g[j] + bv[j];
            }
            *(unsigned int*)&sm_y8[t * YP + d0 + i] = f2e4x4(z[0], z[1], z[2], z[3]);
        }
    }
    __syncthreads();

    // ---- Phase 3: GEMM1 (fp8). Wave owns 16 cols of U (fp8 regs) and 16 of V (-> Vt) ----
    unsigned int u8r[M16];                    // 8*gelu(U) packed fp8x4 [mi]
    {
        f32x4 acc[M16];
        #pragma unroll
        for (int mi = 0; mi < M16; ++mi) acc[mi] = f32x4{0.f, 0.f, 0.f, 0.f};
        const unsigned char* wpu = w1t + (size_t)GROUP * 512 * 256 + (size_t)(wv * 16) * 256;
        __builtin_amdgcn_s_setprio(1);
        #pragma unroll
        for (int k0 = 0; k0 < 256; k0 += 32) {
            i64f a[M16];
            #pragma unroll
            for (int mi = 0; mi < M16; ++mi)
                a[mi] = *(const i64f*)&sm_y8[(16 * mi + l16) * YP + k0 + 8 * l4];
            i64f bb = *(const i64f*)&wpu[(size_t)l16 * 256 + k0 + 8 * l4];
            #pragma unroll
            for (int mi = 0; mi < M16; ++mi)
                acc[mi] = __builtin_amdgcn_mfma_f32_16x16x32_fp8_fp8(a[mi], bb, acc[mi], 0, 0, 0);
        }
        __builtin_amdgcn_s_setprio(0);
        {
            float b1v = b1[GROUP * 512 + wv * 16 + l16];
            #pragma unroll
            for (int mi = 0; mi < M16; ++mi) {
                float z0 = gelu_f(acc[mi][0] * 0.0625f + b1v);
                float z1 = gelu_f(acc[mi][1] * 0.0625f + b1v);
                float z2 = gelu_f(acc[mi][2] * 0.0625f + b1v);
                float z3 = gelu_f(acc[mi][3] * 0.0625f + b1v);
                u8r[mi] = f2e4x4(8.f * z0, 8.f * z1, 8.f * z2, 8.f * z3);
            }
        }
        // V pass
        #pragma unroll
        for (int mi = 0; mi < M16; ++mi) acc[mi] = f32x4{0.f, 0.f, 0.f, 0.f};
        const unsigned char* wpv = w1t + (size_t)GROUP * 512 * 256 + (size_t)(256 + wv * 16) * 256;
        __builtin_amdgcn_s_setprio(1);
        #pragma unroll
        for (int k0 = 0; k0 < 256; k0 += 32) {
            i64f a[M16];
            #pragma unroll
            for (int mi = 0; mi < M16; ++mi)
                a[mi] = *(const i64f*)&sm_y8[(16 * mi + l16) * YP + k0 + 8 * l4];
            i64f bb = *(const i64f*)&wpv[(size_t)l16 * 256 + k0 + 8 * l4];
            #pragma unroll
            for (int mi = 0; mi < M16; ++mi)
                acc[mi] = __builtin_amdgcn_mfma_f32_16x16x32_fp8_fp8(a[mi], bb, acc[mi], 0, 0, 0);
        }
        __builtin_amdgcn_s_setprio(0);
        {
            int row = wv * 16 + l16;                        // V channel -> Vt row
            float b1v = b1[GROUP * 512 + 256 + wv * 16 + l16];
            #pragma unroll
            for (int mi = 0; mi < M16; ++mi) {
                float z0 = gelu_f(acc[mi][0] * 0.0625f + b1v);
                float z1 = gelu_f(acc[mi][1] * 0.0625f + b1v);
                float z2 = gelu_f(acc[mi][2] * 0.0625f + b1v);
                float z3 = gelu_f(acc[mi][3] * 0.0625f + b1v);
                *(unsigned int*)&vt8[row * VTP + 16 * mi + 4 * l4] = f2e4x4(z0, z1, z2, z3);
            }
        }
    }
    __syncthreads();

    // ---- Phase 4: LN (sgu) over Vt columns, in place (fp8) ----
    {
        float s1 = 0.f, s2 = 0.f;
        #pragma unroll
        for (int i = 0; i < CPT; ++i) {
            float f = e42f(vt8[(d0 + i) * VTP + t]);
            s1 += f; s2 += f * f;
        }
        part4[(0 * TPT + dq) * LSEG + t] = s1;
        part4[(1 * TPT + dq) * LSEG + t] = s2;
    }
    __syncthreads();
    {
        float mu = 0.f, sq = 0.f;
        #pragma unroll
        for (int q = 0; q < TPT; ++q) {
            mu += part4[(0 * TPT + q) * LSEG + t];
            sq += part4[(1 * TPT + q) * LSEG + t];
        }
        mu *= (1.0f / DCH);
        float var = sq * (1.0f / DCH) - mu * mu;
        float rs = rsqrtf(var + 1e-5f);
        #pragma unroll
        for (int i = 0; i < CPT; i += 4) {
            f32x4 g  = *(const f32x4*)&sgu_g[GROUP * DCH + d0 + i];
            f32x4 bv = *(const f32x4*)&sgu_b[GROUP * DCH + d0 + i];
            #pragma unroll
            for (int j = 0; j < 4; ++j) {
                int d = d0 + i + j;
                float f = e42f(vt8[d * VTP + t]);
                vt8[d * VTP + t] = f2e4((f - mu) * rs * g[j] + bv[j]);
            }
        }
    }
    __syncthreads();

    // ---- Phase 5: token-mix (fp8)  Vm = (Ws*256)@V / 256 + bs ; P = (8u).*Vm -> Y region ----
    {
        f32x4 acc[M16];
        #pragma unroll
        for (int mi = 0; mi < M16; ++mi) acc[mi] = f32x4{0.f, 0.f, 0.f, 0.f};
        constexpr int KS = (LSEG > 32) ? (LSEG / 32) : 1;
        const int row = wv * 16 + l16;
        __builtin_amdgcn_s_setprio(1);
        #pragma unroll
        for (int ks = 0; ks < KS; ++ks) {
            const int k0 = 32 * ks;
            i64f a[M16], bb;
            #pragma unroll
            for (int mi = 0; mi < M16; ++mi) {
                if constexpr (LSEG == 16)
                    a[mi] = (l4 < 2) ? *(const i64f*)&wsp[(16 * mi + l16) * LSEG + 8 * l4] : (i64f)0;
                else
                    a[mi] = *(const i64f*)&wsp[(16 * mi + l16) * LSEG + k0 + 8 * l4];
            }
            if constexpr (LSEG == 16)
                bb = (l4 < 2) ? *(const i64f*)&vt8[row * VTP + 8 * l4] : (i64f)0;
            else
                bb = *(const i64f*)&vt8[row * VTP + k0 + 8 * l4];
            #pragma unroll
            for (int mi = 0; mi < M16; ++mi)
                acc[mi] = __builtin_amdgcn_mfma_f32_16x16x32_fp8_fp8(a[mi], bb, acc[mi], 0, 0, 0);
        }
        __builtin_amdgcn_s_setprio(0);
        #pragma unroll
        for (int mi = 0; mi < M16; ++mi) {
            #pragma unroll
            for (int r = 0; r < 4; ++r) {
                int m = 16 * mi + 4 * l4 + r;
                float uf = e42f((unsigned char)((u8r[mi] >> (8 * r)) & 0xFF)); // = 8*u
                float p = (acc[mi][r] * (1.0f / 256.0f) + bs[m]) * uf;         // = 8*P
                sm_y8[m * YP + row] = f2e4(p);
            }
        }
    }
    __syncthreads();

    // ---- Phase 6: GEMM2 (fp8)  O = (8P)@(16W2)/128 + b2 -> O_t bf16 (channel-major) ----
    {
        f32x4 acc[M16];
        #pragma unroll
        for (int mi = 0; mi < M16; ++mi) acc[mi] = f32x4{0.f, 0.f, 0.f, 0.f};
        const unsigned char* wp2 = w2t + (size_t)GROUP * 256 * 256 + (size_t)(wv * 16) * 256;
        __builtin_amdgcn_s_setprio(1);
        #pragma unroll
        for (int k0 = 0; k0 < 256; k0 += 32) {
            i64f a[M16];
            #pragma unroll
            for (int mi = 0; mi < M16; ++mi)
                a[mi] = *(const i64f*)&sm_y8[(16 * mi + l16) * YP + k0 + 8 * l4];
            i64f bb = *(const i64f*)&wp2[(size_t)l16 * 256 + k0 + 8 * l4];
            #pragma unroll
            for (int mi = 0; mi < M16; ++mi)
                acc[mi] = __builtin_amdgcn_mfma_f32_16x16x32_fp8_fp8(a[mi], bb, acc[mi], 0, 0, 0);
        }
        __builtin_amdgcn_s_setprio(0);
        __syncthreads();                       // all P reads done before O_t overlays Y+Vt
        const int cu = wv * 16 + l16;
        float b2v = b2[GROUP * DCH + cu];
        #pragma unroll
        for (int mi = 0; mi < M16; ++mi) {
            s16x4 op;
            #pragma unroll
            for (int r = 0; r < 4; ++r)
                op[r] = (short)f2b(acc[mi][r] * (1.0f / 128.0f) + b2v);
            *(s16x4*)&ot16[cu * XTP + 16 * mi + 4 * l4] = op;  // tokens 16mi+4l4..+4
        }
    }
    __syncthreads();

    // ---- Phase 7: coalesced float4 scatter: lane = (channel, 4-px group) ----
    {
        constexpr int NG  = LSEG / 4;          // float4 groups per channel
        constexpr int GPR = PC / 4;            // groups per window row
        constexpr int ITERS = 256 * NG / NT;
        #pragma unroll
        for (int i = 0; i < ITERS; ++i) {
            int f = tid + NT * i;
            int ch = f / NG;
            int g  = f % NG;
            int row = g / GPR, gc = g % GPR;
            int hq2 = (hr0 + row + 4) & (HWD - 1);
            int wq2 = (wr0 + 4 * gc + 4) & (HWD - 1);
            s16x4 ov = *(const s16x4*)&ot16[ch * XTP + 4 * g];
            s16x4 xv = *(const s16x4*)&xt16[ch * XTP + 4 * g];
            f32x4 o;
            #pragma unroll
            for (int j = 0; j < 4; ++j)
                o[j] = b2f((unsigned short)ov[j]) + b2f((unsigned short)xv[j]);
            *(f32x4*)&out[((size_t)b * DCH + ch) * plane + (size_t)hq2 * HWD + wq2] = o;
        }
    }
}

// ---------------- single fused kernel: all 3 segment classes in one grid ----------------
__global__ __launch_bounds__(1024, 4)  // no VGPR squeeze (budget 128); residency via natural alloc
void gmlp_all(const float* __restrict__ x,
              const float* __restrict__ ln1_g, const float* __restrict__ ln1_b,
              const float* __restrict__ b1,
              const float* __restrict__ sgu_g, const float* __restrict__ sgu_b,
              const float* __restrict__ bsf, const float* __restrict__ bsh,
              const float* __restrict__ bsq, const float* __restrict__ b2,
              const unsigned char* __restrict__ w1t, const unsigned char* __restrict__ w2t,
              const unsigned char* __restrict__ wsf, const unsigned char* __restrict__ wsh,
              const unsigned char* __restrict__ wsq,
              float* __restrict__ out)
{
    __shared__ __align__(16) unsigned char smem[70144];
    const int bid = blockIdx.x;

    if (bid < 3600) {                          // full 8x8 windows
        int b = bid / 225, rem = bid % 225;
        int hr0 = (rem / 15) * 8, wr0 = (rem % 15) * 8;
        gmlp_body<64, 0, 8>(b, hr0, wr0,
                            x, ln1_g, ln1_b, b1, sgu_g, sgu_b, bsf, b2, w1t, w2t, wsf, out, smem);
    } else if (bid < 4080) {                   // l / r vertical strips (8 rows x 4 cols)
        int ix = bid - 3600;
        int side = ix / 240, j = ix % 240;
        int b = j / 15, hr0 = (j % 15) * 8, wr0 = 120 + 4 * side;
        gmlp_body<32, 1, 4>(b, hr0, wr0,
                            x, ln1_g, ln1_b, b1, sgu_g, sgu_b, bsh, b2, w1t, w2t, wsh, out, smem);
    } else if (bid < 4560) {                   // u / d horizontal strips (4 rows x 8 cols)
        int ix = bid - 4080;
        int side = ix / 240, j = ix % 240;
        int b = j / 15, hr0 = 120 + 4 * side, wr0 = (j % 15) * 8;
        gmlp_body<32, 1, 8>(b, hr0, wr0,
                            x, ln1_g, ln1_b, b1, sgu_g, sgu_b, bsh, b2, w1t, w2t, wsh, out, smem);
    } else {                                   // quadrants 4x4
        int ix = bid - 4560;
        int quad = ix >> 4, b = ix & 15;
        int hr0 = 120 + 4 * (quad >> 1), wr0 = 120 + 4 * (quad & 1);
        gmlp_body<16, 2, 4>(b, hr0, wr0,
                            x, ln1_g, ln1_b, b1, sgu_g, sgu_b, bsq, b2, w1t, w2t, wsq, out, smem);
    }
}

extern "C" void kernel_launch(void* const* d_in, const int* in_sizes, int n_in,
                              void* d_out, int out_size, void* d_ws, size_t ws_size,
                              hipStream_t stream)
{
    (void)in_sizes; (void)n_in; (void)out_size; (void)ws_size;
    const float* x     = (const float*)d_in[0];
    const float* ln1_g = (const float*)d_in[1];
    const float* ln1_b = (const float*)d_in[2];
    const float* W1    = (const float*)d_in[3];
    const float* b1    = (const float*)d_in[4];
    const float* sgu_g = (const float*)d_in[5];
    const float* sgu_b = (const float*)d_in[6];
    const float* Wsf   = (const float*)d_in[7];
    const float* bsf   = (const float*)d_in[8];
    const float* Wsh   = (const float*)d_in[9];
    const float* bsh   = (const float*)d_in[10];
    const float* Wsq   = (const float*)d_in[11];
    const float* bsq   = (const float*)d_in[12];
    const float* W2    = (const float*)d_in[13];
    const float* b2    = (const float*)d_in[14];
    float* out = (float*)d_out;

    unsigned char* w1t = (unsigned char*)d_ws;   // 3*512*256 fp8
    unsigned char* w2t = w1t + 3 * 512 * 256;    // 3*256*256 fp8
    unsigned char* wsf = w2t + 3 * 256 * 256;    // 64*64
    unsigned char* wsh = wsf + 64 * 64;          // 32*32
    unsigned char* wsq = wsh + 32 * 32;          // 16*16

    hipLaunchKernelGGL(prep_weights, dim3(1536), dim3(256), 0, stream,
                       W1, W2, Wsf, Wsh, Wsq, w1t, w2t, wsf, wsh, wsq);

    hipLaunchKernelGGL(gmlp_all, dim3(4624), dim3(1024), 0, stream,
                       x, ln1_g, ln1_b, b1, sgu_g, sgu_b,
                       bsf, bsh, bsq, b2, w1t, w2t, wsf, wsh, wsq, out);
}

// Round 12
// 396.393 us; speedup vs baseline: 1.4091x; 1.4091x over previous
//
#include <hip/hip_runtime.h>
#include <hip/hip_bf16.h>
#include <math.h>

#define DCH 256
#define HWD 128

typedef __attribute__((ext_vector_type(4))) float f32x4;
typedef __attribute__((ext_vector_type(4))) short s16x4;
typedef long long i64f;   // 8 packed fp8 (2 VGPR) MFMA operand

__device__ __forceinline__ float b2f(unsigned short u) {
    union { float f; unsigned int i; } c; c.i = ((unsigned int)u) << 16; return c.f;
}
__device__ __forceinline__ unsigned short f2b(float f) {
    union { __hip_bfloat16 h; unsigned short u; } c; c.h = __float2bfloat16(f); return c.u;
}
__device__ __forceinline__ unsigned int f2b2(float lo, float hi) {
    return (unsigned int)f2b(lo) | ((unsigned int)f2b(hi) << 16);
}
// fp8 e4m3 (OCP on gfx950) conversions
__device__ __forceinline__ unsigned char f2e4(float f) {
    return (unsigned char)(__builtin_amdgcn_cvt_pk_fp8_f32(f, 0.f, 0, false) & 0xFF);
}
__device__ __forceinline__ unsigned int f2e4x4(float a, float b, float c, float d) {
    unsigned int lo = (unsigned int)__builtin_amdgcn_cvt_pk_fp8_f32(a, b, 0, false);
    return (unsigned int)__builtin_amdgcn_cvt_pk_fp8_f32(c, d, (int)lo, true);
}
__device__ __forceinline__ float e42f(unsigned char u) {
    return __builtin_amdgcn_cvt_f32_fp8((int)u, 0);
}
// sigmoid-form gelu: z * sigma(1.702 z) (absmax-verified in R9 run: 0.03125)
__device__ __forceinline__ float gelu_f(float z) {
    return z / (1.0f + exp2f(-2.455407f * z));
}

// ---- weight prep: fp32 -> scaled fp8 (W1,W2 x16; Ws x256), W1/W2 transposed ----
__global__ void prep_weights(const float* __restrict__ W1, const float* __restrict__ W2,
                             const float* __restrict__ Wsf, const float* __restrict__ Wsh,
                             const float* __restrict__ Wsq,
                             unsigned char* __restrict__ w1t, unsigned char* __restrict__ w2t,
                             unsigned char* __restrict__ wsf, unsigned char* __restrict__ wsh,
                             unsigned char* __restrict__ wsq)
{
    int idx = blockIdx.x * 256 + threadIdx.x;
    if (idx < 3 * 512 * 256) {               // w1t[g][n][k] = 16*W1[g][k][n]
        int g = idx / (512 * 256); int r = idx % (512 * 256);
        int n = r / 256, k = r % 256;
        w1t[idx] = f2e4(16.0f * W1[((size_t)g * 256 + k) * 512 + n]);
    }
    if (idx < 3 * 256 * 256) {               // w2t[g][n][k] = 16*W2[g][k][n]
        int g = idx / (256 * 256); int r = idx % (256 * 256);
        int n = r / 256, k = r % 256;
        w2t[idx] = f2e4(16.0f * W2[((size_t)g * 256 + k) * 256 + n]);
    }
    if (idx < 64 * 64) wsf[idx] = f2e4(256.0f * Wsf[idx]);
    if (idx < 32 * 32) wsh[idx] = f2e4(256.0f * Wsh[idx]);
    if (idx < 16 * 16) wsq[idx] = f2e4(256.0f * Wsq[idx]);
}

// ---------------- fused per-segment gMLP body: 512 threads (8 waves), fp8 LDS ----------------
// LDS: X_t bf16 [256][LSEG+4] (residual, channel-major)
//      Y fp8 [LSEG][264] -> P(fp8)  ;  Vt fp8 [256][LSEG+8]
//      O_t bf16 [256][LSEG+4] overlays Y+Vt after GEMM2 barrier.
template<int LSEG, int GROUP, int PC>
__device__ __forceinline__
void gmlp_body(int b, int hr0, int wr0,
               const float* __restrict__ x,
               const float* __restrict__ ln1_g, const float* __restrict__ ln1_b,
               const float* __restrict__ b1,
               const float* __restrict__ sgu_g, const float* __restrict__ sgu_b,
               const float* __restrict__ bs, const float* __restrict__ b2,
               const unsigned char* __restrict__ w1t,
               const unsigned char* __restrict__ w2t,
               const unsigned char* __restrict__ wsp,
               float* __restrict__ out,
               unsigned char* smem)
{
    constexpr int TPT = 512 / LSEG;
    constexpr int CPT = DCH / TPT;
    constexpr int YP  = 264;                  // Y fp8 row stride (bytes)
    constexpr int M16 = LSEG / 16;
    constexpr int XTP = LSEG + 4;             // X_t / O_t row stride (u16 elements)
    constexpr int VTP = LSEG + 8;             // Vt row stride (bytes)
    constexpr int SZXT = 256 * XTP * 2;
    constexpr int SZY  = LSEG * YP;
    constexpr int SZVT = 256 * VTP;
    static_assert(SZXT + SZY + SZVT <= 70144, "LDS budget");
    static_assert(SZY + SZVT >= SZXT, "O_t must fit over Y+Vt");
    static_assert(SZVT >= 2 * 512 * 4 && SZY >= 2 * 512 * 4, "stats fit");

    unsigned short* xt16 = (unsigned short*)smem;      // X_t (bf16, channel-major)
    unsigned char*  sm_y8 = smem + SZXT;               // Y (fp8), later P (fp8)
    unsigned char*  vt8   = smem + SZXT + SZY;         // Vt (fp8)
    float* part1 = (float*)(smem + SZXT + SZY);        // stats ph1-2 (Vt dead)
    float* part4 = (float*)(smem + SZXT);              // stats ph4 (Y dead)
    unsigned short* ot16 = (unsigned short*)(smem + SZXT); // O_t bf16 (after barrier)

    const int tid  = threadIdx.x;
    const int lane = tid & 63;
    const int wv   = tid >> 6;                // 0..7
    const int l16  = lane & 15;
    const int l4   = lane >> 4;
    const int t    = tid & (LSEG - 1);
    const int dq   = tid / LSEG;
    const int d0   = dq * CPT;

    const int pr = t / PC, pc = t % PC;
    const int hq = (hr0 + pr + 4) & (HWD - 1);
    const int wq = (wr0 + pc + 4) & (HWD - 1);
    const size_t plane = (size_t)HWD * HWD;
    const float* xp = x + (size_t)b * DCH * plane + (size_t)hq * HWD + wq;

    // ---- Phase 1: gather x + stats; residual -> xres regs AND X_t (channel-major) ----
    unsigned int xres[CPT / 2];
    {
        float s1 = 0.f, s2 = 0.f;
        #pragma unroll
        for (int i = 0; i < CPT; i += 2) {
            float v0 = xp[(size_t)(d0 + i) * plane];
            float v1 = xp[(size_t)(d0 + i + 1) * plane];
            s1 += v0 + v1; s2 += v0 * v0 + v1 * v1;
            unsigned int pk = f2b2(v0, v1);
            xres[i / 2] = pk;
            xt16[(d0 + i) * XTP + t]     = (unsigned short)(pk & 0xFFFF);
            xt16[(d0 + i + 1) * XTP + t] = (unsigned short)(pk >> 16);
        }
        part1[(0 * TPT + dq) * LSEG + t] = s1;
        part1[(1 * TPT + dq) * LSEG + t] = s2;
    }
    __syncthreads();

    // ---- Phase 2: LN1 -> Y (fp8) ----
    {
        float mu = 0.f, sq = 0.f;
        #pragma unroll
        for (int q = 0; q < TPT; ++q) {
            mu += part1[(0 * TPT + q) * LSEG + t];
            sq += part1[(1 * TPT + q) * LSEG + t];
        }
        mu *= (1.0f / DCH);
        float var = sq * (1.0f / DCH) - mu * mu;
        float rs = rsqrtf(var + 1e-5f);
        #pragma unroll
        for (int i = 0; i < CPT; i += 4) {
            f32x4 g  = *(const f32x4*)&ln1_g[GROUP * DCH + d0 + i];
            f32x4 bv = *(const f32x4*)&ln1_b[GROUP * DCH + d0 + i];
            float z[4];
            #pragma unroll
            for (int j = 0; j < 4; ++j) {
                unsigned int pk = xres[(i + j) / 2];
                float v = b2f((unsigned short)((j & 1) ? (pk >> 16) : (pk & 0xFFFF)));
                z[j] = (v - mu) * rs * g[j] + bv[j];
            }
            *(unsigned int*)&sm_y8[t * YP + d0 + i] = f2e4x4(z[0], z[1], z[2], z[3]);
        }
    }
    __syncthreads();

    // ---- Phase 3: GEMM1 (fp8). Wave owns 32 cols of U (fp8 regs) and 32 of V (-> Vt) ----
    unsigned int u8[M16][2];                  // 8*gelu(U) packed fp8x4 [mi][ni]
    {
        f32x4 acc[M16][2];
        #pragma unroll
        for (int mi = 0; mi < M16; ++mi) { acc[mi][0] = f32x4{0,0,0,0}; acc[mi][1] = f32x4{0,0,0,0}; }
        const unsigned char* wpu = w1t + (size_t)GROUP * 512 * 256 + (size_t)(wv * 32) * 256;
        __builtin_amdgcn_s_setprio(1);
        #pragma unroll
        for (int k0 = 0; k0 < 256; k0 += 32) {
            i64f a[M16], bb[2];
            #pragma unroll
            for (int mi = 0; mi < M16; ++mi)
                a[mi] = *(const i64f*)&sm_y8[(16 * mi + l16) * YP + k0 + 8 * l4];
            #pragma unroll
            for (int ni = 0; ni < 2; ++ni)
                bb[ni] = *(const i64f*)&wpu[(size_t)(16 * ni + l16) * 256 + k0 + 8 * l4];
            #pragma unroll
            for (int mi = 0; mi < M16; ++mi)
                #pragma unroll
                for (int ni = 0; ni < 2; ++ni)
                    acc[mi][ni] = __builtin_amdgcn_mfma_f32_16x16x32_fp8_fp8(a[mi], bb[ni], acc[mi][ni], 0, 0, 0);
        }
        __builtin_amdgcn_s_setprio(0);
        #pragma unroll
        for (int ni = 0; ni < 2; ++ni) {
            float b1v = b1[GROUP * 512 + wv * 32 + 16 * ni + l16];
            #pragma unroll
            for (int mi = 0; mi < M16; ++mi) {
                float z0 = gelu_f(acc[mi][ni][0] * 0.0625f + b1v);
                float z1 = gelu_f(acc[mi][ni][1] * 0.0625f + b1v);
                float z2 = gelu_f(acc[mi][ni][2] * 0.0625f + b1v);
                float z3 = gelu_f(acc[mi][ni][3] * 0.0625f + b1v);
                u8[mi][ni] = f2e4x4(8.f * z0, 8.f * z1, 8.f * z2, 8.f * z3);
            }
        }
        // V pass
        #pragma unroll
        for (int mi = 0; mi < M16; ++mi) { acc[mi][0] = f32x4{0,0,0,0}; acc[mi][1] = f32x4{0,0,0,0}; }
        const unsigned char* wpv = w1t + (size_t)GROUP * 512 * 256 + (size_t)(256 + wv * 32) * 256;
        __builtin_amdgcn_s_setprio(1);
        #pragma unroll
        for (int k0 = 0; k0 < 256; k0 += 32) {
            i64f a[M16], bb[2];
            #pragma unroll
            for (int mi = 0; mi < M16; ++mi)
                a[mi] = *(const i64f*)&sm_y8[(16 * mi + l16) * YP + k0 + 8 * l4];
            #pragma unroll
            for (int ni = 0; ni < 2; ++ni)
                bb[ni] = *(const i64f*)&wpv[(size_t)(16 * ni + l16) * 256 + k0 + 8 * l4];
            #pragma unroll
            for (int mi = 0; mi < M16; ++mi)
                #pragma unroll
                for (int ni = 0; ni < 2; ++ni)
                    acc[mi][ni] = __builtin_amdgcn_mfma_f32_16x16x32_fp8_fp8(a[mi], bb[ni], acc[mi][ni], 0, 0, 0);
        }
        __builtin_amdgcn_s_setprio(0);
        #pragma unroll
        for (int ni = 0; ni < 2; ++ni) {
            int row = wv * 32 + 16 * ni + l16;              // V channel -> Vt row
            float b1v = b1[GROUP * 512 + 256 + wv * 32 + 16 * ni + l16];
            #pragma unroll
            for (int mi = 0; mi < M16; ++mi) {
                float z0 = gelu_f(acc[mi][ni][0] * 0.0625f + b1v);
                float z1 = gelu_f(acc[mi][ni][1] * 0.0625f + b1v);
                float z2 = gelu_f(acc[mi][ni][2] * 0.0625f + b1v);
                float z3 = gelu_f(acc[mi][ni][3] * 0.0625f + b1v);
                *(unsigned int*)&vt8[row * VTP + 16 * mi + 4 * l4] = f2e4x4(z0, z1, z2, z3);
            }
        }
    }
    __syncthreads();

    // ---- Phase 4: LN (sgu) over Vt columns, in place (fp8) ----
    {
        float s1 = 0.f, s2 = 0.f;
        #pragma unroll
        for (int i = 0; i < CPT; ++i) {
            float f = e42f(vt8[(d0 + i) * VTP + t]);
            s1 += f; s2 += f * f;
        }
        part4[(0 * TPT + dq) * LSEG + t] = s1;
        part4[(1 * TPT + dq) * LSEG + t] = s2;
    }
    __syncthreads();
    {
        float mu = 0.f, sq = 0.f;
        #pragma unroll
        for (int q = 0; q < TPT; ++q) {
            mu += part4[(0 * TPT + q) * LSEG + t];
            sq += part4[(1 * TPT + q) * LSEG + t];
        }
        mu *= (1.0f / DCH);
        float var = sq * (1.0f / DCH) - mu * mu;
        float rs = rsqrtf(var + 1e-5f);
        #pragma unroll
        for (int i = 0; i < CPT; i += 4) {
            f32x4 g  = *(const f32x4*)&sgu_g[GROUP * DCH + d0 + i];
            f32x4 bv = *(const f32x4*)&sgu_b[GROUP * DCH + d0 + i];
            #pragma unroll
            for (int j = 0; j < 4; ++j) {
                int d = d0 + i + j;
                float f = e42f(vt8[d * VTP + t]);
                vt8[d * VTP + t] = f2e4((f - mu) * rs * g[j] + bv[j]);
            }
        }
    }
    __syncthreads();

    // ---- Phase 5: token-mix (fp8)  Vm = (Ws*256)@V / 256 + bs ; P = (8u).*Vm -> Y region ----
    {
        f32x4 acc[M16][2];
        #pragma unroll
        for (int mi = 0; mi < M16; ++mi) { acc[mi][0] = f32x4{0,0,0,0}; acc[mi][1] = f32x4{0,0,0,0}; }
        constexpr int KS = (LSEG > 32) ? (LSEG / 32) : 1;
        __builtin_amdgcn_s_setprio(1);
        #pragma unroll
        for (int ks = 0; ks < KS; ++ks) {
            const int k0 = 32 * ks;
            i64f a[M16], bb[2];
            #pragma unroll
            for (int mi = 0; mi < M16; ++mi) {
                if constexpr (LSEG == 16)
                    a[mi] = (l4 < 2) ? *(const i64f*)&wsp[(16 * mi + l16) * LSEG + 8 * l4] : (i64f)0;
                else
                    a[mi] = *(const i64f*)&wsp[(16 * mi + l16) * LSEG + k0 + 8 * l4];
            }
            #pragma unroll
            for (int ni = 0; ni < 2; ++ni) {
                int row = wv * 32 + 16 * ni + l16;
                if constexpr (LSEG == 16)
                    bb[ni] = (l4 < 2) ? *(const i64f*)&vt8[row * VTP + 8 * l4] : (i64f)0;
                else
                    bb[ni] = *(const i64f*)&vt8[row * VTP + k0 + 8 * l4];
            }
            #pragma unroll
            for (int mi = 0; mi < M16; ++mi)
                #pragma unroll
                for (int ni = 0; ni < 2; ++ni)
                    acc[mi][ni] = __builtin_amdgcn_mfma_f32_16x16x32_fp8_fp8(a[mi], bb[ni], acc[mi][ni], 0, 0, 0);
        }
        __builtin_amdgcn_s_setprio(0);
        #pragma unroll
        for (int mi = 0; mi < M16; ++mi) {
            #pragma unroll
            for (int r = 0; r < 4; ++r) {
                int m = 16 * mi + 4 * l4 + r;
                float bsm = bs[m];
                #pragma unroll
                for (int ni = 0; ni < 2; ++ni) {
                    float uf = e42f((unsigned char)((u8[mi][ni] >> (8 * r)) & 0xFF)); // = 8*u
                    float p = (acc[mi][ni][r] * (1.0f / 256.0f) + bsm) * uf;          // = 8*P
                    sm_y8[m * YP + wv * 32 + 16 * ni + l16] = f2e4(p);
                }
            }
        }
    }
    __syncthreads();

    // ---- Phase 6: GEMM2 (fp8)  O = (8P)@(16W2)/128 + b2 -> O_t bf16 (channel-major) ----
    {
        f32x4 acc[M16][2];
        #pragma unroll
        for (int mi = 0; mi < M16; ++mi) { acc[mi][0] = f32x4{0,0,0,0}; acc[mi][1] = f32x4{0,0,0,0}; }
        const int nb2 = wv * 32;
        const unsigned char* wp2 = w2t + (size_t)GROUP * 256 * 256 + (size_t)nb2 * 256;
        __builtin_amdgcn_s_setprio(1);
        #pragma unroll
        for (int k0 = 0; k0 < 256; k0 += 32) {
            i64f a[M16], bb[2];
            #pragma unroll
            for (int mi = 0; mi < M16; ++mi)
                a[mi] = *(const i64f*)&sm_y8[(16 * mi + l16) * YP + k0 + 8 * l4];
            #pragma unroll
            for (int ni = 0; ni < 2; ++ni)
                bb[ni] = *(const i64f*)&wp2[(size_t)(16 * ni + l16) * 256 + k0 + 8 * l4];
            #pragma unroll
            for (int mi = 0; mi < M16; ++mi)
                #pragma unroll
                for (int ni = 0; ni < 2; ++ni)
                    acc[mi][ni] = __builtin_amdgcn_mfma_f32_16x16x32_fp8_fp8(a[mi], bb[ni], acc[mi][ni], 0, 0, 0);
        }
        __builtin_amdgcn_s_setprio(0);
        __syncthreads();                       // all P reads done before O_t overlays Y+Vt
        #pragma unroll
        for (int ni = 0; ni < 2; ++ni) {
            int cu = nb2 + 16 * ni + l16;
            float b2v = b2[GROUP * DCH + cu];
            #pragma unroll
            for (int mi = 0; mi < M16; ++mi) {
                s16x4 op;
                #pragma unroll
                for (int r = 0; r < 4; ++r)
                    op[r] = (short)f2b(acc[mi][ni][r] * (1.0f / 128.0f) + b2v);
                *(s16x4*)&ot16[cu * XTP + 16 * mi + 4 * l4] = op;  // tokens 16mi+4l4..+4
            }
        }
    }
    __syncthreads();

    // ---- Phase 7: coalesced float4 scatter: lane = (channel, 4-px group) ----
    {
        constexpr int NG  = LSEG / 4;          // float4 groups per channel
        constexpr int GPR = PC / 4;            // groups per window row
        constexpr int ITERS = 256 * NG / 512;
        #pragma unroll
        for (int i = 0; i < ITERS; ++i) {
            int f = tid + 512 * i;
            int ch = f / NG;
            int g  = f % NG;
            int row = g / GPR, gc = g % GPR;
            int hq2 = (hr0 + row + 4) & (HWD - 1);
            int wq2 = (wr0 + 4 * gc + 4) & (HWD - 1);
            s16x4 ov = *(const s16x4*)&ot16[ch * XTP + 4 * g];
            s16x4 xv = *(const s16x4*)&xt16[ch * XTP + 4 * g];
            f32x4 o;
            #pragma unroll
            for (int j = 0; j < 4; ++j)
                o[j] = b2f((unsigned short)ov[j]) + b2f((unsigned short)xv[j]);
            *(f32x4*)&out[((size_t)b * DCH + ch) * plane + (size_t)hq2 * HWD + wq2] = o;
        }
    }
}

// ---------------- single fused kernel: all 3 segment classes in one grid ----------------
// XCD-pairing swizzle: all 15 window-columns of one (batch, window-row) land on the SAME
// XCD (assuming round-robin XCD = blockIdx % 8), so the 32B window-row write segments of
// adjacent columns merge into full 64B lines in one L2 (kills write RMW amplification).
__global__ __launch_bounds__(512, 4)
void gmlp_all(const float* __restrict__ x,
              const float* __restrict__ ln1_g, const float* __restrict__ ln1_b,
              const float* __restrict__ b1,
              const float* __restrict__ sgu_g, const float* __restrict__ sgu_b,
              const float* __restrict__ bsf, const float* __restrict__ bsh,
              const float* __restrict__ bsq, const float* __restrict__ b2,
              const unsigned char* __restrict__ w1t, const unsigned char* __restrict__ w2t,
              const unsigned char* __restrict__ wsf, const unsigned char* __restrict__ wsh,
              const unsigned char* __restrict__ wsq,
              float* __restrict__ out)
{
    __shared__ __align__(16) unsigned char smem[70144];
    const int bid = blockIdx.x;

    if (bid < 3600) {                          // full 8x8 windows: group (b,r) -> XCD g%8
        int xcd = bid & 7;
        int q   = bid >> 3;                    // [0,450)
        int gq  = q / 15, j = q % 15;          // gq in [0,30), j = window column
        int g   = gq * 8 + xcd;                // group id in [0,240)
        int b = g / 15, r = g % 15;
        gmlp_body<64, 0, 8>(b, r * 8, j * 8,
                            x, ln1_g, ln1_b, b1, sgu_g, sgu_b, bsf, b2, w1t, w2t, wsf, out, smem);
    } else if (bid < 4080) {                   // l/r strips: natural order already aligns
        int ix = bid - 3600;                   // XCD = ix%8 = (b*15+r)%8 = full-window group
        int side = ix / 240, j = ix % 240;
        int b = j / 15, hr0 = (j % 15) * 8, wr0 = 120 + 4 * side;
        gmlp_body<32, 1, 4>(b, hr0, wr0,
                            x, ln1_g, ln1_b, b1, sgu_g, sgu_b, bsh, b2, w1t, w2t, wsh, out, smem);
    } else if (bid < 4560) {                   // u/d strips: group (side,b) -> same XCD
        int off = bid - 4080;                  // [0,480); 4080 % 8 == 0
        int xcd = off & 7;
        int q   = off >> 3;                    // [0,60)
        int gq  = q / 15, c = q % 15;          // gq in [0,4)
        int g2  = gq * 8 + xcd;                // [0,32)
        int side = g2 >> 4, b = g2 & 15;
        gmlp_body<32, 1, 8>(b, 120 + 4 * side, c * 8,
                            x, ln1_g, ln1_b, b1, sgu_g, sgu_b, bsh, b2, w1t, w2t, wsh, out, smem);
    } else {                                   // quadrants 4x4 (64 blocks, negligible)
        int ix = bid - 4560;
        int quad = ix >> 4, b = ix & 15;
        int hr0 = 120 + 4 * (quad >> 1), wr0 = 120 + 4 * (quad & 1);
        gmlp_body<16, 2, 4>(b, hr0, wr0,
                            x, ln1_g, ln1_b, b1, sgu_g, sgu_b, bsq, b2, w1t, w2t, wsq, out, smem);
    }
}

extern "C" void kernel_launch(void* const* d_in, const int* in_sizes, int n_in,
                              void* d_out, int out_size, void* d_ws, size_t ws_size,
                              hipStream_t stream)
{
    (void)in_sizes; (void)n_in; (void)out_size; (void)ws_size;
    const float* x     = (const float*)d_in[0];
    const float* ln1_g = (const float*)d_in[1];
    const float* ln1_b = (const float*)d_in[2];
    const float* W1    = (const float*)d_in[3];
    const float* b1    = (const float*)d_in[4];
    const float* sgu_g = (const float*)d_in[5];
    const float* sgu_b = (const float*)d_in[6];
    const float* Wsf   = (const float*)d_in[7];
    const float* bsf   = (const float*)d_in[8];
    const float* Wsh   = (const float*)d_in[9];
    const float* bsh   = (const float*)d_in[10];
    const float* Wsq   = (const float*)d_in[11];
    const float* bsq   = (const float*)d_in[12];
    const float* W2    = (const float*)d_in[13];
    const float* b2    = (const float*)d_in[14];
    float* out = (float*)d_out;

    unsigned char* w1t = (unsigned char*)d_ws;   // 3*512*256 fp8
    unsigned char* w2t = w1t + 3 * 512 * 256;    // 3*256*256 fp8
    unsigned char* wsf = w2t + 3 * 256 * 256;    // 64*64
    unsigned char* wsh = wsf + 64 * 64;          // 32*32
    unsigned char* wsq = wsh + 32 * 32;          // 16*16

    hipLaunchKernelGGL(prep_weights, dim3(1536), dim3(256), 0, stream,
                       W1, W2, Wsf, Wsh, Wsq, w1t, w2t, wsf, wsh, wsq);

    hipLaunchKernelGGL(gmlp_all, dim3(4624), dim3(512), 0, stream,
                       x, ln1_g, ln1_b, b1, sgu_g, sgu_b,
                       bsf, bsh, bsq, b2, w1t, w2t, wsf, wsh, wsq, out);
}